// Round 2
// baseline (296.330 us; speedup 1.0000x reference)
//
#include <hip/hip_runtime.h>
#include <hip/hip_bf16.h>
#include <cstdint>

// KANLinear fused as ONE bf16 GEMM, K = 1024*8 (spline basis) + 1024 (silu) = 9216.
//   A[b, 8i+k]   = basis_k(x[b,i]);  A[b, 8192+i] = silu(x[b,i])
//   W[o, 8i+k]   = spline_weight[o,i,k];  W[o, 8192+i] = base_weight[o,i]
// out = A @ W^T  (M=8192, N=1024, K=9216), fp32 in/out, bf16 MFMA internal.
//
// R11 = R10 (256x256 deep-pipelined GEMM, T3+T4+T5) + race hardening:
//   - sched_barrier(0) between prologue STAGEs: without it the MIR scheduler
//     may interleave the 12 prologue global_load_lds ops across STAGE
//     boundaries, breaking the "oldest 4 = tile 0" vmcnt(8) accounting.
//     (In-loop STAGEs were already fenced by surrounding sched_barriers.)
//   - tail prefetch clamped to restage tile 0 (same vmcnt count; avoids
//     reading past the K-split into adjacent ws buffers).
// Schedule recap:
//   - split-K=2 -> grid 4x32x2 = 256 WGs = exactly 1 block/CU, + fp32 reduce
//   - BK=32, 3-buffer LDS ring (96 KB): counted s_waitcnt vmcnt(8) at the
//     tile boundary (tiles t+2,t+3 stay in flight; never drain to 0),
//     raw s_barrier (no compiler vmcnt(0)), sched_barrier(0) fences (rule 18)
//   - WAR on the ring slot ordered by a mid-iter lgkmcnt(0)+barrier BEFORE
//     the t+3 stage overwrites buf[t%3]  -> race-free by construction
//   - BK=32 row stride = 64 B -> ds_read_b128 address set per 16-row group
//     is a dense 1 KB block (same bank distribution as linear b128)
//   - s_setprio(1) around the 32-MFMA cluster (T5)
//   - XCD swizzle: each XCD gets 8 contiguous rowBands x 4 colBands of one
//     K-split so the 4 blocks reading an A panel share one L2.

typedef short s16x8 __attribute__((ext_vector_type(8)));   // 8 bf16 in 4 VGPRs
typedef float f32x4 __attribute__((ext_vector_type(4)));

#define GK 9216
#define GN 1024
#define GI 1024
#define GM 8192

#define BK 32
#define KSPLIT 4608          // GK/2
#define NT 144               // KSPLIT/BK

#define BS_BLK 32768   // basis+silu: 8192*1024 threads (1 per x)
#define RP_BLK 4608    // repack   : 1024*1152 threads (8 cols each)

__device__ __forceinline__ void cp16(const __hip_bfloat16* g, __hip_bfloat16* l) {
  __builtin_amdgcn_global_load_lds((const __attribute__((address_space(1))) void*)g,
                                   (__attribute__((address_space(3))) void*)l, 16, 0, 0);
}

__device__ __forceinline__ uint32_t bfbits(float f) {   // RTNE bf16 bits, SSA only
  __hip_bfloat16 h = __float2bfloat16(f);
  unsigned short us;
  __builtin_memcpy(&us, &h, 2);
  return (uint32_t)us;
}

__device__ __forceinline__ void basis4(float xv, int& jj, float& w0, float& w1,
                                       float& w2, float& w3) {
  float t = fminf(1.f, fmaxf(-1.f, xv));
  float us = (t + 1.f) * 2.5f;          // (t - grid[3]) / h, grid[3]=-1, h=0.4
  int j = (int)us;
  if (j > 4) j = 4;                     // t==1.0 edge: matches reference exactly
  float u = us - (float)j;
  float u2 = u * u, u3 = u2 * u;
  float om = 1.f - u;
  jj = j;
  w0 = om * om * om * (1.f / 6.f);
  w1 = (3.f * u3 - 6.f * u2 + 4.f) * (1.f / 6.f);
  w2 = (-3.f * u3 + 3.f * u2 + 3.f * u + 1.f) * (1.f / 6.f);
  w3 = u3 * (1.f / 6.f);
}

// --- ONE dispatch: basis+silu (1 thread/x) + weight repack -----------------
__global__ void kan_prep_all(const float* __restrict__ x,
                             const float* __restrict__ baseW,
                             const float* __restrict__ splineW,
                             __hip_bfloat16* __restrict__ W2,
                             __hip_bfloat16* __restrict__ A) {
  int bid = blockIdx.x;
  if (bid < BS_BLK) {
    int t = bid * 256 + threadIdx.x;        // [0, 8192*1024)
    int b = t >> 10, i = t & 1023;
    float xv = x[t];

    // silu -> A[b, 8192+i], 2 B coalesced store
    float sl = xv / (1.f + __expf(-xv));
    A[(size_t)b * GK + 8192 + i] = __float2bfloat16(sl);

    // basis -> A[b, 8i..8i+7]: funnel-shift packed weights into window jj,
    // one dense 16 B store per lane (stride-16 across the wave)
    int jj; float w0, w1, w2, w3;
    basis4(xv, jj, w0, w1, w2, w3);
    uint64_t W64 = (uint64_t)(bfbits(w0) | (bfbits(w1) << 16)) |
                   ((uint64_t)(bfbits(w2) | (bfbits(w3) << 16)) << 32);
    int sh = jj * 16;                                  // 0,16,32,48,64
    uint64_t lo = (jj < 4) ? (W64 << sh) : 0ull;       // guard UB at sh=64
    uint64_t hi = (jj == 0) ? 0ull : (W64 >> (64 - sh));
    uint4 pk;
    pk.x = (uint32_t)lo;  pk.y = (uint32_t)(lo >> 32);
    pk.z = (uint32_t)hi;  pk.w = (uint32_t)(hi >> 32);
    *(uint4*)(A + (size_t)b * GK + (size_t)i * 8) = pk;
  } else {
    // repack: thread handles 8 cols (32 B fp32 in, 16 B bf16 out)
    int t = (bid - BS_BLK) * 256 + threadIdx.x;   // [0, 1024*1152)
    int o = t / 1152;
    int c = (t - o * 1152) * 8;
    const float* src = (c < 8192) ? (splineW + (size_t)o * 8192 + c)
                                  : (baseW + (size_t)o * GI + (c - 8192));
    float4 v0 = ((const float4*)src)[0];
    float4 v1 = ((const float4*)src)[1];
    uint4 pk;
    pk.x = bfbits(v0.x) | (bfbits(v0.y) << 16);
    pk.y = bfbits(v0.z) | (bfbits(v0.w) << 16);
    pk.z = bfbits(v1.x) | (bfbits(v1.y) << 16);
    pk.w = bfbits(v1.z) | (bfbits(v1.w) << 16);
    *(uint4*)(W2 + (size_t)o * GK + c) = pk;
  }
}

// --- R11 GEMM: 256x256 tile, BK=32, 3-buf ring, counted vmcnt, split-K=2 ---
__global__ __launch_bounds__(512, 2) void kan_gemm8(
    const __hip_bfloat16* __restrict__ A,   // (8192, 9216) bf16
    const __hip_bfloat16* __restrict__ B,   // (1024, 9216) bf16
    float* __restrict__ C0,                 // ksplit 0 -> out
    float* __restrict__ C1) {               // ksplit 1 -> partial
  __shared__ __align__(16) __hip_bfloat16 As[3][256 * BK];   // 48 KB
  __shared__ __align__(16) __hip_bfloat16 Bs[3][256 * BK];   // 48 KB
  const int tid = threadIdx.x;
  const int lane = tid & 63;
  const int wave = tid >> 6;                 // 0..7
  const int wm = wave >> 2, wn = wave & 3;   // 2x4 waves, 128x64 out each

  // XCD swizzle over exactly 256 WGs: xcd = linear%8 owns 32 consecutive c's
  // = 8 rowBands x 4 colBands of one ksplit -> A panels L2-shared per XCD.
  const int linear = (blockIdx.z * 32 + blockIdx.y) * 4 + blockIdx.x;  // 0..255
  const int c = (linear & 7) * 32 + (linear >> 3);
  const int colBand = c & 3;
  const int rowBand = (c >> 2) & 31;
  const int ks = c >> 7;
  const int blockRow = rowBand * 256;
  const int blockCol = colBand * 256;
  const int kbase = ks * KSPLIT;

  // staging: per cp16, 512 lanes x 16 B = 8 KB = 128 rows x 32 k (linear LDS)
  const int srow = tid >> 2;                 // 0..127
  const int sq = tid & 3;
  const __hip_bfloat16* aSrc = A + (size_t)(blockRow + srow) * GK + kbase + sq * 8;
  const __hip_bfloat16* bSrc = B + (size_t)(blockCol + srow) * GK + kbase + sq * 8;
  const int ldsOff = wave * 512;             // wave-uniform; HW adds lane*16 B

#define STAGE(T, BUF)                                             \
  do {                                                            \
    const __hip_bfloat16* ga = aSrc + (T) * BK;                   \
    const __hip_bfloat16* gb = bSrc + (T) * BK;                   \
    cp16(ga, As[BUF] + ldsOff);                                   \
    cp16(ga + 128 * GK, As[BUF] + ldsOff + 4096);                 \
    cp16(gb, Bs[BUF] + ldsOff);                                   \
    cp16(gb + 128 * GK, Bs[BUF] + ldsOff + 4096);                 \
  } while (0)

  const int q = lane >> 4, r16 = lane & 15;
  const int aBase = (wm * 128 + r16) * 4 + q;   // s16x8 index; +tm*64
  const int bBase = (wn * 64 + r16) * 4 + q;    // +tn*64

  f32x4 acc[8][4] = {};

  // prologue: 3 tiles in flight (12 loads), ISSUE-ORDER PINNED per tile so
  // vmcnt(8) really confirms tile 0; then drain to 8.
  STAGE(0, 0);
  __builtin_amdgcn_sched_barrier(0);
  STAGE(1, 1);
  __builtin_amdgcn_sched_barrier(0);
  STAGE(2, 2);
  __builtin_amdgcn_sched_barrier(0);
  asm volatile("s_waitcnt vmcnt(8)" ::: "memory");
  __builtin_amdgcn_sched_barrier(0);
  __builtin_amdgcn_s_barrier();

  for (int t3 = 0; t3 < NT / 3; ++t3) {
#pragma unroll
    for (int u = 0; u < 3; ++u) {
      const int t = t3 * 3 + u;
      // tail guard: last 3 iters restage tile 0 (never read again) to keep
      // the vmcnt count identical without reading past the K-split.
      const int tp = (t + 3 < NT) ? (t + 3) : 0;
      __builtin_amdgcn_sched_barrier(0);
      // frag reads of buf u (tile t) — landed per prev iter's vmcnt+barrier
      const s16x8* Af = (const s16x8*)As[u];
      const s16x8* Bf = (const s16x8*)Bs[u];
      s16x8 af[8], bfg[4];
#pragma unroll
      for (int tm = 0; tm < 8; ++tm) af[tm] = Af[aBase + tm * 64];
#pragma unroll
      for (int tn = 0; tn < 4; ++tn) bfg[tn] = Bf[bBase + tn * 64];
      asm volatile("s_waitcnt lgkmcnt(0)" ::: "memory");
      __builtin_amdgcn_sched_barrier(0);
      __builtin_amdgcn_s_barrier();     // ALL waves done reading buf u
      __builtin_amdgcn_sched_barrier(0);
      STAGE(tp, u);                     // overwrite now safe (WAR ordered)
      __builtin_amdgcn_sched_barrier(0);
      __builtin_amdgcn_s_setprio(1);
#pragma unroll
      for (int tm = 0; tm < 8; ++tm)
#pragma unroll
        for (int tn = 0; tn < 4; ++tn)
          acc[tm][tn] = __builtin_amdgcn_mfma_f32_16x16x32_bf16(
              af[tm], bfg[tn], acc[tm][tn], 0, 0, 0);
      __builtin_amdgcn_s_setprio(0);
      // counted: 8 newest loads (tiles t+2, t+3) stay in flight; tile t+1
      // (oldest 4 of the 12) is confirmed. Never drain to 0 in the loop.
      asm volatile("s_waitcnt vmcnt(8)" ::: "memory");
      __builtin_amdgcn_sched_barrier(0);
      __builtin_amdgcn_s_barrier();
    }
  }
  // drain the tail prefetches before LDS goes away
  asm volatile("s_waitcnt vmcnt(0)" ::: "memory");

  float* __restrict__ Cd = ks ? C1 : C0;
  // C/D layout: col = lane&15, row = (lane>>4)*4 + reg  [m89-verified]
  const int cRow0 = blockRow + wm * 128 + q * 4;
  const int cCol0 = blockCol + wn * 64 + r16;
#pragma unroll
  for (int tm = 0; tm < 8; ++tm)
#pragma unroll
    for (int tn = 0; tn < 4; ++tn) {
      int col = cCol0 + tn * 16;
      size_t base = (size_t)(cRow0 + tm * 16) * GN + col;
#pragma unroll
      for (int r = 0; r < 4; ++r)
        Cd[base + (size_t)r * GN] = acc[tm][tn][r];
    }
#undef STAGE
}

// --- reduce: out += partial (both fp32, 8192x1024) -------------------------
__global__ void kan_reduce(float* __restrict__ out, const float* __restrict__ part) {
  size_t i = ((size_t)blockIdx.x * 256 + threadIdx.x) * 4;
  float4 a = *(const float4*)(out + i);
  float4 b = *(const float4*)(part + i);
  a.x += b.x; a.y += b.y; a.z += b.z; a.w += b.w;
  *(float4*)(out + i) = a;
}

// --- fallback GEMM (R9): 512 threads, 128x128 tile, BK=64 dual BK=32 bufs --
__global__ __launch_bounds__(512) void kan_gemm(
    const __hip_bfloat16* __restrict__ A,   // (8192, 9216) bf16
    const __hip_bfloat16* __restrict__ B,   // (1024, 9216) bf16
    float* __restrict__ C) {                // (8192, 1024) fp32
  __shared__ __align__(16) __hip_bfloat16 Asf[2][128 * 32];   // 16 KB
  __shared__ __align__(16) __hip_bfloat16 Bsf[2][128 * 32];   // 16 KB
  const int tid = threadIdx.x;
  const int lane = tid & 63;
  const int wave = tid >> 6;                 // 0..7
  const int wm = wave >> 2, wn = wave & 3;   // 2x4 waves, 64x32 each

  const int linear = blockIdx.y * 8 + blockIdx.x;
  const int rowBand = (linear & 7) * 8 + ((linear >> 3) & 7);
  const int colBand = linear >> 6;
  const int blockRow = rowBand * 128;
  const int blockCol = colBand * 128;

  const __hip_bfloat16* aPtr = A + (size_t)(blockRow + (tid >> 2)) * GK + (tid & 3) * 8;
  const __hip_bfloat16* bPtr = B + (size_t)(blockCol + (tid >> 2)) * GK + (tid & 3) * 8;
  __hip_bfloat16* ldsA0 = Asf[0] + wave * 512;
  __hip_bfloat16* ldsA1 = Asf[1] + wave * 512;
  __hip_bfloat16* ldsB0 = Bsf[0] + wave * 512;
  __hip_bfloat16* ldsB1 = Bsf[1] + wave * 512;

  f32x4 acc[4][2] = {};

  const int q = lane >> 4;
  const int r16 = lane & 15;
  const int aRow = wm * 64 + r16;
  const int bRow = wn * 32 + r16;

  for (int kt = 0; kt < GK / 64; ++kt) {        // 144 iters
    cp16(aPtr, ldsA0);
    cp16(aPtr + 32, ldsA1);
    cp16(bPtr, ldsB0);
    cp16(bPtr + 32, ldsB1);
    aPtr += 64; bPtr += 64;
    __syncthreads();

#pragma unroll
    for (int s = 0; s < 2; ++s) {
      const s16x8* Af = (const s16x8*)Asf[s];
      const s16x8* Bf = (const s16x8*)Bsf[s];
      s16x8 af[4], bfg[2];
#pragma unroll
      for (int tm = 0; tm < 4; ++tm) af[tm] = Af[(aRow + tm * 16) * 4 + q];
#pragma unroll
      for (int tn = 0; tn < 2; ++tn) bfg[tn] = Bf[(bRow + tn * 16) * 4 + q];
#pragma unroll
      for (int tm = 0; tm < 4; ++tm)
#pragma unroll
        for (int tn = 0; tn < 2; ++tn)
          acc[tm][tn] = __builtin_amdgcn_mfma_f32_16x16x32_bf16(
              af[tm], bfg[tn], acc[tm][tn], 0, 0, 0);
    }
    __syncthreads();
  }

  const int cRow0 = blockRow + wm * 64 + q * 4;
  const int cCol0 = blockCol + wn * 32 + r16;
#pragma unroll
  for (int tm = 0; tm < 4; ++tm)
#pragma unroll
    for (int tn = 0; tn < 2; ++tn) {
      int col = cCol0 + tn * 16;
#pragma unroll
      for (int r = 0; r < 4; ++r) {
        int row = cRow0 + tm * 16 + r;
        C[(size_t)row * GN + col] = acc[tm][tn][r];
      }
    }
}

// --- emergency fallback if ws_size is too small ----------------------------
__global__ void kan_naive(const float* __restrict__ x,
                          const float* __restrict__ bw,
                          const float* __restrict__ sw,
                          float* __restrict__ out) {
  int o = blockIdx.x * 256 + threadIdx.x;
  int b = blockIdx.y;
  float acc = 0.f;
  for (int i = 0; i < GI; ++i) {
    float xv = x[(size_t)b * GI + i];
    float sl = xv / (1.f + __expf(-xv));
    acc += sl * bw[(size_t)o * GI + i];
    int jj; float w0, w1, w2, w3;
    basis4(xv, jj, w0, w1, w2, w3);
    const float* swr = sw + ((size_t)o * GI + i) * 8 + jj;
    acc += w0 * swr[0] + w1 * swr[1] + w2 * swr[2] + w3 * swr[3];
  }
  out[(size_t)b * GN + o] = acc;
}

extern "C" void kernel_launch(void* const* d_in, const int* in_sizes, int n_in,
                              void* d_out, int out_size, void* d_ws, size_t ws_size,
                              hipStream_t stream) {
  const float* x  = (const float*)d_in[0];   // (8192, 1024) fp32
  const float* bw = (const float*)d_in[1];   // (1024, 1024) fp32
  const float* sw = (const float*)d_in[2];   // (1024, 1024, 8) fp32
  float* out = (float*)d_out;                // (8192, 1024) fp32

  const size_t wBytes = (size_t)GK * GN * 2;   // 18.9 MB repacked weights
  const size_t aBytes = (size_t)GM * GK * 2;   // 151 MB activations
  const size_t pBytes = (size_t)GM * GN * 4;   // 33.6 MB split-K partial

  if (ws_size < wBytes + aBytes) {
    kan_naive<<<dim3(GN / 256, GM), 256, 0, stream>>>(x, bw, sw, out);
    return;
  }

  __hip_bfloat16* W2 = (__hip_bfloat16*)d_ws;
  __hip_bfloat16* Abuf = W2 + (size_t)GK * GN;       // 16B-aligned

  kan_prep_all<<<BS_BLK + RP_BLK, 256, 0, stream>>>(x, bw, sw, W2, Abuf);

  if (ws_size >= wBytes + aBytes + pBytes) {
    float* partial = (float*)((char*)d_ws + wBytes + aBytes);
    kan_gemm8<<<dim3(4, 32, 2), 512, 0, stream>>>(Abuf, W2, out, partial);
    kan_reduce<<<GM * GN / (256 * 4), 256, 0, stream>>>(out, partial);
  } else {
    kan_gemm<<<dim3(GN / 128, GM / 128), 512, 0, stream>>>(Abuf, W2, out);
  }
}